// Round 1
// baseline (619.702 us; speedup 1.0000x reference)
//
#include <hip/hip_runtime.h>

// GraphProjection: per-point perspective projection + 4-level bilinear gather.
// Output row layout: [X,Y,Z, out1(64), out2(128), out3(256), out4(512)] = 963 f32.
// Wave-per-point: 64 lanes cover the channel dim -> coalesced row writes.

template <int C, int G>
__device__ __forceinline__ void project_level(const float* __restrict__ f,
                                              float x, float y,
                                              float* __restrict__ o, int lane) {
    // x = row coord (from h), y = col coord (from w); feat[xi, yi, c]
    float x1 = floorf(x), x2 = ceilf(x);
    float y1 = floorf(y), y2 = ceilf(y);
    int xi1 = (int)x1, xi2 = (int)x2;
    int yi1 = (int)y1, yi2 = (int)y2;
    // JAX gather clamps OOB indices (ceil can reach G); weights use unclamped x2/y2.
    xi1 = min(xi1, G - 1); xi2 = min(xi2, G - 1);
    yi1 = min(yi1, G - 1); yi2 = min(yi2, G - 1);

    float wx2 = x2 - x, wx1 = x - x1;   // weights along rows
    float wy2 = y2 - y, wy1 = y - y1;   // weights along cols
    float w11 = wx2 * wy2;
    float w21 = wx1 * wy2;
    float w12 = wx2 * wy1;
    float w22 = wx1 * wy1;

    const float* q11 = f + (size_t)(xi1 * G + yi1) * C;
    const float* q12 = f + (size_t)(xi1 * G + yi2) * C;
    const float* q21 = f + (size_t)(xi2 * G + yi1) * C;
    const float* q22 = f + (size_t)(xi2 * G + yi2) * C;

#pragma unroll
    for (int c = lane; c < C; c += 64) {
        // same accumulation order as reference: ((w11*Q11 + w21*Q21) + w12*Q12) + w22*Q22
        float v = w11 * q11[c] + w21 * q21[c] + w12 * q12[c] + w22 * q22[c];
        o[c] = v;
    }
}

__global__ void __launch_bounds__(256)
graph_projection_kernel(const float* __restrict__ coord,
                        const float* __restrict__ f1,
                        const float* __restrict__ f2,
                        const float* __restrict__ f3,
                        const float* __restrict__ f4,
                        float* __restrict__ out, int n) {
    const int lane = threadIdx.x & 63;
    const int wid  = (blockIdx.x * blockDim.x + threadIdx.x) >> 6;
    const int nw   = (gridDim.x * blockDim.x) >> 6;

    for (int p = wid; p < n; p += nw) {
        float X = coord[3 * p + 0];
        float Y = coord[3 * p + 1];
        float Z = coord[3 * p + 2];
        // reference: h = 248*(-Y/-Z)+112 ; w = 248*(X/-Z)+112 ; Z <= -1 so -Z >= 1
        float h = 248.0f * (Y / Z) + 112.0f;       // (-Y)/(-Z) == Y/Z exactly (IEEE)
        float w = 248.0f * (X / (-Z)) + 112.0f;
        h = fminf(fmaxf(h, 0.0f), 223.0f);
        w = fminf(fmaxf(w, 0.0f), 223.0f);

        float* orow = out + (size_t)p * 963;
        if (lane < 3) orow[lane] = coord[3 * p + lane];

        // scale divisors 4/8/16/32 are pow2 -> exact reciprocal multiply
        project_level<64, 56>(f1, h * 0.25f,    w * 0.25f,    orow + 3,   lane);
        project_level<128, 28>(f2, h * 0.125f,  w * 0.125f,   orow + 67,  lane);
        project_level<256, 14>(f3, h * 0.0625f, w * 0.0625f,  orow + 195, lane);
        project_level<512, 7>(f4, h * 0.03125f, w * 0.03125f, orow + 451, lane);
    }
}

extern "C" void kernel_launch(void* const* d_in, const int* in_sizes, int n_in,
                              void* d_out, int out_size, void* d_ws, size_t ws_size,
                              hipStream_t stream) {
    const float* coord = (const float*)d_in[0];
    const float* f1 = (const float*)d_in[1];
    const float* f2 = (const float*)d_in[2];
    const float* f3 = (const float*)d_in[3];
    const float* f4 = (const float*)d_in[4];
    float* out = (float*)d_out;

    const int n = in_sizes[0] / 3;  // 131072 points

    dim3 block(256);
    dim3 grid(2048);  // memory-bound: cap blocks, grid-stride (G11)
    graph_projection_kernel<<<grid, block, 0, stream>>>(coord, f1, f2, f3, f4, out, n);
}

// Round 2
// 582.919 us; speedup vs baseline: 1.0631x; 1.0631x over previous
//
#include <hip/hip_runtime.h>

// GraphProjection: perspective projection + 4-level bilinear gather.
// Output row: [X,Y,Z, L1(64), L2(128), L3(256), L4(512)] = 963 f32, N=131072 rows.
//
// Layout: each wave processes a GROUP of 4 consecutive points so that every
// level uses all 64 lanes at float4 width:
//   L1 (C=64):  16 lanes/point x 4 points, 1 float4 store
//   L2 (C=128): 32 lanes/point x 2 points, 2 iterations
//   L3 (C=256): 64 lanes/point, 4 iterations
//   L4 (C=512): 64 lanes/point x 2 chunks, 4 iterations
// Gather loads are 16B-aligned (feature rows are C*4B multiples). Output rows
// are only 4B-aligned (963 floats/row) -> aligned(4) vector stores, nontemporal.

typedef float f4 __attribute__((ext_vector_type(4)));
typedef f4 uf4 __attribute__((aligned(4)));   // under-aligned store type

struct BL {
    f4  wt;                    // w11, w21, w12, w22
    int b11, b21, b12, b22;    // row base in float4 units
};

template <int C, int G>
__device__ __forceinline__ BL make_bl(float x, float y) {
    // x = scaled h (first index), y = scaled w (second index)
    float x1 = floorf(x), x2 = ceilf(x);
    float y1 = floorf(y), y2 = ceilf(y);
    int xi1 = min((int)x1, G - 1), xi2 = min((int)x2, G - 1);
    int yi1 = min((int)y1, G - 1), yi2 = min((int)y2, G - 1);
    float wx2 = x2 - x, wx1 = x - x1;
    float wy2 = y2 - y, wy1 = y - y1;
    BL r;
    r.wt = (f4){wx2 * wy2, wx1 * wy2, wx2 * wy1, wx1 * wy1};
    const int W = C / 4;
    r.b11 = (xi1 * G + yi1) * W;
    r.b21 = (xi2 * G + yi1) * W;
    r.b12 = (xi1 * G + yi2) * W;
    r.b22 = (xi2 * G + yi2) * W;
    return r;
}

__device__ __forceinline__ f4 blend(const f4* __restrict__ f, const BL& b, int cc) {
    f4 q11 = f[b.b11 + cc];
    f4 q21 = f[b.b21 + cc];
    f4 q12 = f[b.b12 + cc];
    f4 q22 = f[b.b22 + cc];
    // reference order: ((w11*Q11 + w21*Q21) + w12*Q12) + w22*Q22
    return b.wt.x * q11 + b.wt.y * q21 + b.wt.z * q12 + b.wt.w * q22;
}

__device__ __forceinline__ void proj_hw(const float* __restrict__ coord, int p,
                                        float& h, float& w) {
    float X = coord[3 * p + 0];
    float Y = coord[3 * p + 1];
    float Z = coord[3 * p + 2];
    float hh = 248.0f * (Y / Z) + 112.0f;        // (-Y)/(-Z) == Y/Z (IEEE exact)
    float ww = 248.0f * (X / (-Z)) + 112.0f;
    h = fminf(fmaxf(hh, 0.0f), 223.0f);
    w = fminf(fmaxf(ww, 0.0f), 223.0f);
}

__global__ void __launch_bounds__(256)
graph_projection_v2(const float* __restrict__ coord,
                    const f4* __restrict__ f1, const f4* __restrict__ f2,
                    const f4* __restrict__ f3, const f4* __restrict__ f4p,
                    float* __restrict__ out, int n) {
    const int lane = threadIdx.x & 63;
    const int wid  = (blockIdx.x * blockDim.x + threadIdx.x) >> 6;
    const int nw   = (gridDim.x * blockDim.x) >> 6;
    const int ngrp = n >> 2;

    for (int g = wid; g < ngrp; g += nw) {
        const int q = g * 4;
        float h[4], w[4];
#pragma unroll
        for (int j = 0; j < 4; ++j) proj_hw(coord, q + j, h[j], w[j]);

        // coord passthrough: 12 floats
        if (lane < 12) {
            int j = lane / 3, k = lane - 3 * j;
            __builtin_nontemporal_store(coord[3 * q + lane],
                                        out + (size_t)963 * (q + j) + k);
        }

        // ---- L1: C=64, 16 lanes/point, all 4 points in one shot ----
        {
            float hj = (lane & 32) ? ((lane & 16) ? h[3] : h[2])
                                   : ((lane & 16) ? h[1] : h[0]);
            float wj = (lane & 32) ? ((lane & 16) ? w[3] : w[2])
                                   : ((lane & 16) ? w[1] : w[0]);
            BL b = make_bl<64, 56>(hj * 0.25f, wj * 0.25f);
            f4 v = blend(f1, b, lane & 15);
            int j = lane >> 4;
            __builtin_nontemporal_store(
                v, (uf4*)(out + (size_t)963 * (q + j) + 3 + 4 * (lane & 15)));
        }

        // ---- L2: C=128, 32 lanes/point, 2 points per iteration ----
#pragma unroll
        for (int jj = 0; jj < 2; ++jj) {
            float hj = (lane & 32) ? h[2 * jj + 1] : h[2 * jj];
            float wj = (lane & 32) ? w[2 * jj + 1] : w[2 * jj];
            BL b = make_bl<128, 28>(hj * 0.125f, wj * 0.125f);
            f4 v = blend(f2, b, lane & 31);
            int j = 2 * jj + (lane >> 5);
            __builtin_nontemporal_store(
                v, (uf4*)(out + (size_t)963 * (q + j) + 67 + 4 * (lane & 31)));
        }

        // ---- L3: C=256, whole wave per point ----
#pragma unroll
        for (int j = 0; j < 4; ++j) {
            BL b = make_bl<256, 14>(h[j] * 0.0625f, w[j] * 0.0625f);
            f4 v = blend(f3, b, lane);
            __builtin_nontemporal_store(
                v, (uf4*)(out + (size_t)963 * (q + j) + 195 + 4 * lane));
        }

        // ---- L4: C=512, whole wave per point, 2 chunks ----
#pragma unroll
        for (int j = 0; j < 4; ++j) {
            BL b = make_bl<512, 7>(h[j] * 0.03125f, w[j] * 0.03125f);
            f4 v0 = blend(f4p, b, lane);
            f4 v1 = blend(f4p, b, lane + 64);
            float* base = out + (size_t)963 * (q + j) + 451;
            __builtin_nontemporal_store(v0, (uf4*)(base + 4 * lane));
            __builtin_nontemporal_store(v1, (uf4*)(base + 256 + 4 * lane));
        }
    }

    // tail (n not divisible by 4 — not hit for N=131072, kept for safety)
    for (int p = (n & ~3) + wid; p < n; p += nw) {
        float h0, w0;
        proj_hw(coord, p, h0, w0);
        if (lane < 3) out[(size_t)963 * p + lane] = coord[3 * p + lane];
        {
            BL b = make_bl<64, 56>(h0 * 0.25f, w0 * 0.25f);
            if (lane < 16) {
                f4 v = blend(f1, b, lane);
                *(uf4*)(out + (size_t)963 * p + 3 + 4 * lane) = v;
            }
        }
        {
            BL b = make_bl<128, 28>(h0 * 0.125f, w0 * 0.125f);
            if (lane < 32) {
                f4 v = blend(f2, b, lane);
                *(uf4*)(out + (size_t)963 * p + 67 + 4 * lane) = v;
            }
        }
        {
            BL b = make_bl<256, 14>(h0 * 0.0625f, w0 * 0.0625f);
            f4 v = blend(f3, b, lane);
            *(uf4*)(out + (size_t)963 * p + 195 + 4 * lane) = v;
        }
        {
            BL b = make_bl<512, 7>(h0 * 0.03125f, w0 * 0.03125f);
            f4 v0 = blend(f4p, b, lane);
            f4 v1 = blend(f4p, b, lane + 64);
            *(uf4*)(out + (size_t)963 * p + 451 + 4 * lane) = v0;
            *(uf4*)(out + (size_t)963 * p + 451 + 256 + 4 * lane) = v1;
        }
    }
}

extern "C" void kernel_launch(void* const* d_in, const int* in_sizes, int n_in,
                              void* d_out, int out_size, void* d_ws, size_t ws_size,
                              hipStream_t stream) {
    const float* coord = (const float*)d_in[0];
    const f4* f1 = (const f4*)d_in[1];
    const f4* f2 = (const f4*)d_in[2];
    const f4* f3 = (const f4*)d_in[3];
    const f4* f4p = (const f4*)d_in[4];
    float* out = (float*)d_out;

    const int n = in_sizes[0] / 3;  // 131072 points

    dim3 block(256);
    dim3 grid(2048);  // 8192 waves -> 4 point-groups per wave
    graph_projection_v2<<<grid, block, 0, stream>>>(coord, f1, f2, f3, f4p, out, n);
}

// Round 3
// 541.478 us; speedup vs baseline: 1.1445x; 1.0765x over previous
//
#include <hip/hip_runtime.h>

// GraphProjection: perspective projection + 4-level bilinear gather.
// Output row: [X,Y,Z, L1(64), L2(128), L3(256), L4(512)] = 963 f32, N=131072.
//
// v3: wave computes a group of 4 consecutive points into a PRIVATE LDS region
// (3852 floats), then streams the whole 15408B block to global with ALIGNED
// wave-wide dwordx4 nontemporal stores (group base = g*15408B, 16B-aligned).
// v2's stores were 4B-aligned (963-float rows) + nt -> partial-sector writes.
//
// Compute mapping per group of 4 points (all 64 lanes busy at f4 width):
//   L1 (C=64):  16 lanes/point x 4 points
//   L2 (C=128): 32 lanes/point x 2 points x 2 iters
//   L3 (C=256): 64 lanes/point x 4 iters
//   L4 (C=512): 64 lanes/point x 2 chunks x 4 iters

typedef float f4 __attribute__((ext_vector_type(4)));
typedef f4 uf4 __attribute__((aligned(4)));   // for the (rare) unaligned tail path

struct BL {
    f4  wt;                    // w11, w21, w12, w22
    int b11, b21, b12, b22;    // feature row bases in float4 units
};

template <int C, int G>
__device__ __forceinline__ BL make_bl(float x, float y) {
    float x1 = floorf(x), x2 = ceilf(x);
    float y1 = floorf(y), y2 = ceilf(y);
    int xi1 = min((int)x1, G - 1), xi2 = min((int)x2, G - 1);
    int yi1 = min((int)y1, G - 1), yi2 = min((int)y2, G - 1);
    float wx2 = x2 - x, wx1 = x - x1;
    float wy2 = y2 - y, wy1 = y - y1;
    BL r;
    r.wt = (f4){wx2 * wy2, wx1 * wy2, wx2 * wy1, wx1 * wy1};
    const int W = C / 4;
    r.b11 = (xi1 * G + yi1) * W;
    r.b21 = (xi2 * G + yi1) * W;
    r.b12 = (xi1 * G + yi2) * W;
    r.b22 = (xi2 * G + yi2) * W;
    return r;
}

__device__ __forceinline__ f4 blend(const f4* __restrict__ f, const BL& b, int cc) {
    f4 q11 = f[b.b11 + cc];
    f4 q21 = f[b.b21 + cc];
    f4 q12 = f[b.b12 + cc];
    f4 q22 = f[b.b22 + cc];
    // reference order: ((w11*Q11 + w21*Q21) + w12*Q12) + w22*Q22
    return b.wt.x * q11 + b.wt.y * q21 + b.wt.z * q12 + b.wt.w * q22;
}

__device__ __forceinline__ void proj_hw(const float* __restrict__ coord, int p,
                                        float& h, float& w) {
    float X = coord[3 * p + 0];
    float Y = coord[3 * p + 1];
    float Z = coord[3 * p + 2];
    float hh = 248.0f * (Y / Z) + 112.0f;        // (-Y)/(-Z) == Y/Z (IEEE exact)
    float ww = 248.0f * (X / (-Z)) + 112.0f;
    h = fminf(fmaxf(hh, 0.0f), 223.0f);
    w = fminf(fmaxf(ww, 0.0f), 223.0f);
}

__device__ __forceinline__ void lds_put4(float* __restrict__ p, f4 v) {
    p[0] = v.x; p[1] = v.y; p[2] = v.z; p[3] = v.w;   // 4B-aligned LDS writes
}

#define WAVE_LDS 3856   // 3852 floats + pad -> 15424B stride, 16B-aligned

__global__ void __launch_bounds__(256)
graph_projection_v3(const float* __restrict__ coord,
                    const f4* __restrict__ f1, const f4* __restrict__ f2,
                    const f4* __restrict__ f3, const f4* __restrict__ f4p,
                    float* __restrict__ out, int n) {
    __shared__ __align__(16) float lds[4 * WAVE_LDS];
    const int lane = threadIdx.x & 63;
    const int wv   = threadIdx.x >> 6;
    float* __restrict__ lb = lds + wv * WAVE_LDS;

    const int wid  = (blockIdx.x * blockDim.x + threadIdx.x) >> 6;
    const int nw   = (gridDim.x * blockDim.x) >> 6;
    const int ngrp = n >> 2;

    for (int g = wid; g < ngrp; g += nw) {
        const int q = g * 4;
        float h[4], w[4];
#pragma unroll
        for (int j = 0; j < 4; ++j) proj_hw(coord, q + j, h[j], w[j]);

        // coord passthrough into LDS rows
        if (lane < 12) {
            int j = lane / 3, k = lane - 3 * j;
            lb[j * 963 + k] = coord[3 * q + lane];
        }

        // ---- L1: C=64, 16 lanes/point ----
        {
            float hj = (lane & 32) ? ((lane & 16) ? h[3] : h[2])
                                   : ((lane & 16) ? h[1] : h[0]);
            float wj = (lane & 32) ? ((lane & 16) ? w[3] : w[2])
                                   : ((lane & 16) ? w[1] : w[0]);
            BL b = make_bl<64, 56>(hj * 0.25f, wj * 0.25f);
            f4 v = blend(f1, b, lane & 15);
            int j = lane >> 4;
            lds_put4(lb + j * 963 + 3 + 4 * (lane & 15), v);
        }

        // ---- L2: C=128, 32 lanes/point ----
#pragma unroll
        for (int jj = 0; jj < 2; ++jj) {
            float hj = (lane & 32) ? h[2 * jj + 1] : h[2 * jj];
            float wj = (lane & 32) ? w[2 * jj + 1] : w[2 * jj];
            BL b = make_bl<128, 28>(hj * 0.125f, wj * 0.125f);
            f4 v = blend(f2, b, lane & 31);
            int j = 2 * jj + (lane >> 5);
            lds_put4(lb + j * 963 + 67 + 4 * (lane & 31), v);
        }

        // ---- L3: C=256, whole wave per point ----
#pragma unroll
        for (int j = 0; j < 4; ++j) {
            BL b = make_bl<256, 14>(h[j] * 0.0625f, w[j] * 0.0625f);
            f4 v = blend(f3, b, lane);
            lds_put4(lb + j * 963 + 195 + 4 * lane, v);
        }

        // ---- L4: C=512, whole wave per point, 2 chunks ----
#pragma unroll
        for (int j = 0; j < 4; ++j) {
            BL b = make_bl<512, 7>(h[j] * 0.03125f, w[j] * 0.03125f);
            f4 v0 = blend(f4p, b, lane);
            f4 v1 = blend(f4p, b, lane + 64);
            lds_put4(lb + j * 963 + 451 + 4 * lane, v0);
            lds_put4(lb + j * 963 + 451 + 256 + 4 * lane, v1);
        }

        // ---- aligned streaming store: 3852 floats = 963 f4 = 15*64 + 3 ----
        // group base byte offset = g*15408, divisible by 16 -> aligned dwordx4
        const f4* __restrict__ lv = (const f4*)lb;
        f4* __restrict__ gb = (f4*)(out + (size_t)3852 * g);
#pragma unroll
        for (int k = 0; k < 15; ++k)
            __builtin_nontemporal_store(lv[(k << 6) + lane], gb + (k << 6) + lane);
        if (lane < 3)
            __builtin_nontemporal_store(lv[960 + lane], gb + 960 + lane);
    }

    // tail (n not divisible by 4 — not hit for N=131072, kept for safety)
    for (int p = (n & ~3) + wid; p < n; p += nw) {
        float h0, w0;
        proj_hw(coord, p, h0, w0);
        if (lane < 3) out[(size_t)963 * p + lane] = coord[3 * p + lane];
        {
            BL b = make_bl<64, 56>(h0 * 0.25f, w0 * 0.25f);
            if (lane < 16) {
                f4 v = blend(f1, b, lane);
                *(uf4*)(out + (size_t)963 * p + 3 + 4 * lane) = v;
            }
        }
        {
            BL b = make_bl<128, 28>(h0 * 0.125f, w0 * 0.125f);
            if (lane < 32) {
                f4 v = blend(f2, b, lane);
                *(uf4*)(out + (size_t)963 * p + 67 + 4 * lane) = v;
            }
        }
        {
            BL b = make_bl<256, 14>(h0 * 0.0625f, w0 * 0.0625f);
            f4 v = blend(f3, b, lane);
            *(uf4*)(out + (size_t)963 * p + 195 + 4 * lane) = v;
        }
        {
            BL b = make_bl<512, 7>(h0 * 0.03125f, w0 * 0.03125f);
            f4 v0 = blend(f4p, b, lane);
            f4 v1 = blend(f4p, b, lane + 64);
            *(uf4*)(out + (size_t)963 * p + 451 + 4 * lane) = v0;
            *(uf4*)(out + (size_t)963 * p + 451 + 256 + 4 * lane) = v1;
        }
    }
}

extern "C" void kernel_launch(void* const* d_in, const int* in_sizes, int n_in,
                              void* d_out, int out_size, void* d_ws, size_t ws_size,
                              hipStream_t stream) {
    const float* coord = (const float*)d_in[0];
    const f4* f1 = (const f4*)d_in[1];
    const f4* f2 = (const f4*)d_in[2];
    const f4* f3 = (const f4*)d_in[3];
    const f4* f4p = (const f4*)d_in[4];
    float* out = (float*)d_out;

    const int n = in_sizes[0] / 3;  // 131072 points

    dim3 block(256);
    dim3 grid(2048);
    graph_projection_v3<<<grid, block, 0, stream>>>(coord, f1, f2, f3, f4p, out, n);
}

// Round 6
// 524.769 us; speedup vs baseline: 1.1809x; 1.0318x over previous
//
#include <hip/hip_runtime.h>

// GraphProjection: perspective projection + 4-level bilinear gather.
// Output row: [X,Y,Z, L1(64), L2(128), L3(256), L4(512)] = 963 f32, N=131072.
//
// v5 = v4 + LDS ordering fences. v4's index algebra is verified; its failure
// is attributed to compile-time reordering of f4 LDS writes vs scalar LDS
// reads across phase boundaries (TBAA float vs <4 x float>). Same-wave DS ops
// are in-order in HW, so pinning compiler order with a memory clobber +
// sched_barrier(0) at each phase transition enforces correctness.
//
// Structure: per group of 4 points, two phases. Each phase computes 2 points
// into a 1928-float LDS buffer (row stride 964: [X Y Z pad | L1 L2 L3 L4]),
// all staging writes ds_write_b128, then flushes with aligned wave-wide
// dwordx4 nontemporal stores (flush reads map m -> m + j + (k>=3)).
// LDS/wave = 7712B -> 5 blocks/CU target via __launch_bounds__(256,5).

typedef float f4 __attribute__((ext_vector_type(4)));
typedef f4 uf4 __attribute__((aligned(4)));   // tail path only

#define LDS_FENCE() do { \
    asm volatile("" ::: "memory"); \
    __builtin_amdgcn_sched_barrier(0); \
} while (0)

struct BL {
    f4  wt;                    // w11, w21, w12, w22
    int b11, b21, b12, b22;    // feature row bases in float4 units
};

template <int C, int G>
__device__ __forceinline__ BL make_bl(float x, float y) {
    float x1 = floorf(x), x2 = ceilf(x);
    float y1 = floorf(y), y2 = ceilf(y);
    int xi1 = min((int)x1, G - 1), xi2 = min((int)x2, G - 1);
    int yi1 = min((int)y1, G - 1), yi2 = min((int)y2, G - 1);
    float wx2 = x2 - x, wx1 = x - x1;
    float wy2 = y2 - y, wy1 = y - y1;
    BL r;
    r.wt = (f4){wx2 * wy2, wx1 * wy2, wx2 * wy1, wx1 * wy1};
    const int W = C / 4;
    r.b11 = (xi1 * G + yi1) * W;
    r.b21 = (xi2 * G + yi1) * W;
    r.b12 = (xi1 * G + yi2) * W;
    r.b22 = (xi2 * G + yi2) * W;
    return r;
}

__device__ __forceinline__ f4 blend(const f4* __restrict__ f, const BL& b, int cc) {
    f4 q11 = f[b.b11 + cc];
    f4 q21 = f[b.b21 + cc];
    f4 q12 = f[b.b12 + cc];
    f4 q22 = f[b.b22 + cc];
    // reference order: ((w11*Q11 + w21*Q21) + w12*Q12) + w22*Q22
    return b.wt.x * q11 + b.wt.y * q21 + b.wt.z * q12 + b.wt.w * q22;
}

__device__ __forceinline__ void proj_hw(const float* __restrict__ coord, int p,
                                        float& h, float& w) {
    float X = coord[3 * p + 0];
    float Y = coord[3 * p + 1];
    float Z = coord[3 * p + 2];
    float hh = 248.0f * (Y / Z) + 112.0f;        // (-Y)/(-Z) == Y/Z (IEEE exact)
    float ww = 248.0f * (X / (-Z)) + 112.0f;
    h = fminf(fmaxf(hh, 0.0f), 223.0f);
    w = fminf(fmaxf(ww, 0.0f), 223.0f);
}

// ---- phase compute: 2 points (p0, p0+1) into LDS rows 0,1 (stride 964) ----
// row layout: 0:X 1:Y 2:Z 3:pad 4..67:L1 68..195:L2 196..451:L3 452..963:L4
__device__ __forceinline__ void compute_phase(float* __restrict__ lb,
                                              const float* __restrict__ coord,
                                              const f4* __restrict__ f1,
                                              const f4* __restrict__ f2,
                                              const f4* __restrict__ f3,
                                              const f4* __restrict__ f4p,
                                              int p0, int lane) {
    float h0, w0, h1, w1;
    proj_hw(coord, p0,     h0, w0);
    proj_hw(coord, p0 + 1, h1, w1);

    if (lane < 6) {
        int j = lane / 3, k = lane - 3 * j;
        lb[j * 964 + k] = coord[3 * p0 + lane];
    }

    // L1: C=64, 16 lanes/point, lanes 0..31
    if (lane < 32) {
        int j = (lane >> 4) & 1;
        float hj = (lane & 16) ? h1 : h0;
        float wj = (lane & 16) ? w1 : w0;
        BL b = make_bl<64, 56>(hj * 0.25f, wj * 0.25f);
        f4 v = blend(f1, b, lane & 15);
        *(f4*)(lb + j * 964 + 4 + 4 * (lane & 15)) = v;
    }
    // L2: C=128, 32 lanes/point, full wave
    {
        int j = lane >> 5;
        float hj = (lane & 32) ? h1 : h0;
        float wj = (lane & 32) ? w1 : w0;
        BL b = make_bl<128, 28>(hj * 0.125f, wj * 0.125f);
        f4 v = blend(f2, b, lane & 31);
        *(f4*)(lb + j * 964 + 68 + 4 * (lane & 31)) = v;
    }
    // L3: C=256, whole wave per point
#pragma unroll
    for (int j = 0; j < 2; ++j) {
        float hj = j ? h1 : h0, wj = j ? w1 : w0;
        BL b = make_bl<256, 14>(hj * 0.0625f, wj * 0.0625f);
        f4 v = blend(f3, b, lane);
        *(f4*)(lb + j * 964 + 196 + 4 * lane) = v;
    }
    // L4: C=512, whole wave per point, 2 chunks
#pragma unroll
    for (int j = 0; j < 2; ++j) {
        float hj = j ? h1 : h0, wj = j ? w1 : w0;
        BL b = make_bl<512, 7>(hj * 0.03125f, wj * 0.03125f);
        f4 v0 = blend(f4p, b, lane);
        f4 v1 = blend(f4p, b, lane + 64);
        *(f4*)(lb + j * 964 + 452 + 4 * lane) = v0;
        *(f4*)(lb + j * 964 + 452 + 256 + 4 * lane) = v1;
    }
}

// output float m of the 2 staged rows (m in [0,1926)) -> LDS float value
__device__ __forceinline__ float lread(const float* __restrict__ lb, int m) {
    int j = (m >= 963) ? 1 : 0;
    int k = m - 963 * j;
    return lb[m + j + (k >= 3 ? 1 : 0)];
}

__global__ void __launch_bounds__(256, 5)
graph_projection_v5(const float* __restrict__ coord,
                    const f4* __restrict__ f1, const f4* __restrict__ f2,
                    const f4* __restrict__ f3, const f4* __restrict__ f4p,
                    float* __restrict__ out, int n) {
    __shared__ __align__(16) float lds[4][1928];   // 7712B per wave, 30.8KB/block
    const int lane = threadIdx.x & 63;
    const int wv   = threadIdx.x >> 6;
    float* __restrict__ lb = lds[wv];

    const int wid  = (blockIdx.x * blockDim.x + threadIdx.x) >> 6;
    const int nw   = (gridDim.x * blockDim.x) >> 6;
    const int ngrp = n >> 2;

    for (int g = wid; g < ngrp; g += nw) {
        const int q = 4 * g;
        f4* __restrict__ gb = (f4*)(out + (size_t)3852 * g);  // 16B-aligned

        // ===== phase A: points q, q+1 -> group f4 0..481 =====
        compute_phase(lb, coord, f1, f2, f3, f4p, q, lane);
        LDS_FENCE();   // all staging writes ordered before flush reads
        {
            const float c2x = coord[3 * (q + 2) + 0];
            const float c2y = coord[3 * (q + 2) + 1];
#pragma unroll
            for (int kk = 0; kk < 7; ++kk) {
                int fi = (kk << 6) + lane;
                int m0 = fi * 4;
                f4 v = {lread(lb, m0), lread(lb, m0 + 1),
                        lread(lb, m0 + 2), lread(lb, m0 + 3)};
                __builtin_nontemporal_store(v, gb + fi);
            }
            if (lane < 34) {
                int fi = 448 + lane;
                int m0 = fi * 4;
                f4 v;
                v.x = lread(lb, m0);
                v.y = lread(lb, m0 + 1);
                if (fi == 481) { v.z = c2x; v.w = c2y; }  // pt2 X,Y (m 1926,1927)
                else { v.z = lread(lb, m0 + 2); v.w = lread(lb, m0 + 3); }
                __builtin_nontemporal_store(v, gb + fi);
            }
        }
        LDS_FENCE();   // flush reads ordered before phase B overwrites

        // ===== phase B: points q+2, q+3 -> group f4 482..962 =====
        compute_phase(lb, coord, f1, f2, f3, f4p, q + 2, lane);
        LDS_FENCE();
        {
#pragma unroll
            for (int kk = 0; kk < 7; ++kk) {
                int fi = 482 + (kk << 6) + lane;
                int m0 = fi * 4 - 1926;   // rel offset into pt2/pt3 rows
                f4 v = {lread(lb, m0), lread(lb, m0 + 1),
                        lread(lb, m0 + 2), lread(lb, m0 + 3)};
                __builtin_nontemporal_store(v, gb + fi);
            }
            if (lane < 33) {
                int fi = 930 + lane;      // f4 930..962, last m = 3851 (rel 1925)
                int m0 = fi * 4 - 1926;
                f4 v = {lread(lb, m0), lread(lb, m0 + 1),
                        lread(lb, m0 + 2), lread(lb, m0 + 3)};
                __builtin_nontemporal_store(v, gb + fi);
            }
        }
        LDS_FENCE();   // flush reads ordered before next iteration's writes
    }

    // tail (n not divisible by 4 — not hit for N=131072, kept for safety)
    for (int p = (n & ~3) + wid; p < n; p += nw) {
        float h0, w0;
        proj_hw(coord, p, h0, w0);
        if (lane < 3) out[(size_t)963 * p + lane] = coord[3 * p + lane];
        {
            BL b = make_bl<64, 56>(h0 * 0.25f, w0 * 0.25f);
            if (lane < 16) {
                f4 v = blend(f1, b, lane);
                *(uf4*)(out + (size_t)963 * p + 3 + 4 * lane) = v;
            }
        }
        {
            BL b = make_bl<128, 28>(h0 * 0.125f, w0 * 0.125f);
            if (lane < 32) {
                f4 v = blend(f2, b, lane);
                *(uf4*)(out + (size_t)963 * p + 67 + 4 * lane) = v;
            }
        }
        {
            BL b = make_bl<256, 14>(h0 * 0.0625f, w0 * 0.0625f);
            f4 v = blend(f3, b, lane);
            *(uf4*)(out + (size_t)963 * p + 195 + 4 * lane) = v;
        }
        {
            BL b = make_bl<512, 7>(h0 * 0.03125f, w0 * 0.03125f);
            f4 v0 = blend(f4p, b, lane);
            f4 v1 = blend(f4p, b, lane + 64);
            *(uf4*)(out + (size_t)963 * p + 451 + 4 * lane) = v0;
            *(uf4*)(out + (size_t)963 * p + 451 + 256 + 4 * lane) = v1;
        }
    }
}

extern "C" void kernel_launch(void* const* d_in, const int* in_sizes, int n_in,
                              void* d_out, int out_size, void* d_ws, size_t ws_size,
                              hipStream_t stream) {
    const float* coord = (const float*)d_in[0];
    const f4* f1 = (const f4*)d_in[1];
    const f4* f2 = (const f4*)d_in[2];
    const f4* f3 = (const f4*)d_in[3];
    const f4* f4p = (const f4*)d_in[4];
    float* out = (float*)d_out;

    const int n = in_sizes[0] / 3;  // 131072 points

    dim3 block(256);
    dim3 grid(2048);
    graph_projection_v5<<<grid, block, 0, stream>>>(coord, f1, f2, f3, f4p, out, n);
}